// Round 1
// baseline (960.035 us; speedup 1.0000x reference)
//
#include <hip/hip_runtime.h>
#include <hip/hip_bf16.h>
#include <stdint.h>

#define NN 100000
#define NE 1600000
#define BNEPS 1e-5f

using short8 = __attribute__((ext_vector_type(8))) short;
using f32x4  = __attribute__((ext_vector_type(4))) float;

__device__ __forceinline__ float b2f(ushort u) {
  union { uint32_t u; float f; } c; c.u = ((uint32_t)u) << 16; return c.f;
}
__device__ __forceinline__ ushort f2bf(float f) {
  union { float f; uint32_t u; } c; c.f = f;
  uint32_t r = (c.u + 0x7FFFu + ((c.u >> 16) & 1u)) >> 16;
  return (ushort)r;
}
__device__ __forceinline__ void gload16(const void* g, void* lds) {
  __builtin_amdgcn_global_load_lds((const __attribute__((address_space(1))) void*)g,
                                   (__attribute__((address_space(3))) void*)lds,
                                   16, 0, 0);
}

// ---------------- CSR build ----------------
__global__ __launch_bounds__(256) void k_deg(const int* __restrict__ dst, int* __restrict__ deg) {
  int stride = gridDim.x * blockDim.x;
  for (int e = blockIdx.x * blockDim.x + threadIdx.x; e < NE; e += stride)
    atomicAdd(&deg[dst[e]], 1);
}

__global__ __launch_bounds__(256) void k_dinv(const int* __restrict__ deg, float* __restrict__ dinv) {
  int v = blockIdx.x * blockDim.x + threadIdx.x;
  if (v < NN) dinv[v] = rsqrtf((float)deg[v] + 1.0f);
}

__global__ __launch_bounds__(256) void k_scan1(const int* __restrict__ deg, int* __restrict__ offs,
                                               int* __restrict__ bsums) {
  __shared__ int s[256];
  int t = threadIdx.x;
  int v = blockIdx.x * 256 + t;
  int d = (v < NN) ? deg[v] : 0;
  s[t] = d; __syncthreads();
  int val = d;
  for (int sh = 1; sh < 256; sh <<= 1) {
    int tv = (t >= sh) ? s[t - sh] : 0;
    __syncthreads();
    val += tv; s[t] = val;
    __syncthreads();
  }
  if (v < NN) offs[v] = val - d;           // block-local exclusive
  if (t == 255) bsums[blockIdx.x] = val;   // block total
}

__global__ __launch_bounds__(512) void k_scan2(int* __restrict__ bsums, int nb, int* __restrict__ offs) {
  __shared__ int s[512];
  int t = threadIdx.x;
  int d = (t < nb) ? bsums[t] : 0;
  s[t] = d; __syncthreads();
  int val = d;
  for (int sh = 1; sh < 512; sh <<= 1) {
    int tv = (t >= sh) ? s[t - sh] : 0;
    __syncthreads();
    val += tv; s[t] = val;
    __syncthreads();
  }
  if (t < nb) bsums[t] = val;              // inclusive
  if (t == 0) offs[NN] = NE;
}

__global__ __launch_bounds__(256) void k_scan3(int* __restrict__ offs, const int* __restrict__ bsums) {
  int v = blockIdx.x * 256 + threadIdx.x;
  if (v < NN) { int b = v >> 8; if (b > 0) offs[v] += bsums[b - 1]; }
}

__global__ __launch_bounds__(256) void k_fill(const int* __restrict__ src, const int* __restrict__ dst,
                                              const int* __restrict__ offs, int* __restrict__ cur,
                                              int* __restrict__ csrc) {
  int stride = gridDim.x * blockDim.x;
  for (int e = blockIdx.x * blockDim.x + threadIdx.x; e < NE; e += stride) {
    int v = dst[e];
    int pos = offs[v] + atomicAdd(&cur[v], 1);
    csrc[pos] = src[e];
  }
}

// ---------------- weight prep: transpose + bf16, BN affine fold ----------------
__global__ __launch_bounds__(256) void k_prep(
    const float* __restrict__ W0, const float* __restrict__ W1, const float* __restrict__ W2,
    const float* __restrict__ W3, const float* __restrict__ b0, const float* __restrict__ b1,
    const float* __restrict__ b2, const float* __restrict__ gamma, const float* __restrict__ beta,
    const float* __restrict__ rm, const float* __restrict__ rv,
    ushort* __restrict__ W0t, ushort* __restrict__ W1t, ushort* __restrict__ W2t,
    ushort* __restrict__ W3t, float* __restrict__ bnA, float* __restrict__ bnB) {
  int tid = blockIdx.x * blockDim.x + threadIdx.x;
  int nthr = gridDim.x * blockDim.x;
  for (int i = tid; i < 256 * 128; i += nthr) { int m = i >> 7, k = i & 127; W0t[i] = f2bf(W0[k * 256 + m]); }
  for (int i = tid; i < 256 * 256; i += nthr) {
    int m = i >> 8, k = i & 255;
    W1t[i] = f2bf(W1[k * 256 + m]);
    W2t[i] = f2bf(W2[k * 256 + m]);
  }
  for (int i = tid; i < 32 * 256; i += nthr) {
    int m = i >> 8, k = i & 255;
    W3t[i] = (m < 20) ? f2bf(W3[k * 20 + m]) : (ushort)0;
  }
  for (int i = tid; i < 3 * 256; i += nthr) {
    int l = i >> 8, c = i & 255;
    float A = gamma[i] * rsqrtf(rv[i] + BNEPS);
    float bb = (l == 0) ? b0[c] : (l == 1) ? b1[c] : b2[c];
    bnA[i] = A;
    bnB[i] = (bb - rm[i]) * A + beta[i];
  }
}

// ---------------- x -> bf16 ----------------
__global__ __launch_bounds__(256) void k_convx(const float4* __restrict__ x, uint2* __restrict__ xb) {
  int stride = gridDim.x * blockDim.x;
  const int n4 = NN * 128 / 4;
  for (int i = blockIdx.x * blockDim.x + threadIdx.x; i < n4; i += stride) {
    float4 f = x[i];
    uint2 o;
    o.x = (uint)f2bf(f.x) | ((uint)f2bf(f.y) << 16);
    o.y = (uint)f2bf(f.z) | ((uint)f2bf(f.w) << 16);
    xb[i] = o;
  }
}

// ---------------- gather aggregation (one wave per node) ----------------
template<int VEC>
__device__ __forceinline__ void loadv(const ushort* p, float* out) {
  if constexpr (VEC == 4) {
    uint2 q = *reinterpret_cast<const uint2*>(p);
    out[0] = b2f((ushort)(q.x & 0xFFFF)); out[1] = b2f((ushort)(q.x >> 16));
    out[2] = b2f((ushort)(q.y & 0xFFFF)); out[3] = b2f((ushort)(q.y >> 16));
  } else {
    uint q = *reinterpret_cast<const uint*>(p);
    out[0] = b2f((ushort)(q & 0xFFFF)); out[1] = b2f((ushort)(q >> 16));
  }
}

template<int F, int VEC>
__global__ __launch_bounds__(256) void k_agg(const ushort* __restrict__ Z,
                                             const int* __restrict__ offs, const int* __restrict__ csrc,
                                             const float* __restrict__ dinv, ushort* __restrict__ Outb) {
  int wave = threadIdx.x >> 6, lane = threadIdx.x & 63;
  int v = blockIdx.x * 4 + wave;
  if (v >= NN) return;
  float dv = dinv[v];
  float acc[VEC], tmp[VEC];
  loadv<VEC>(Z + (size_t)v * F + lane * VEC, acc);
#pragma unroll
  for (int j = 0; j < VEC; ++j) acc[j] *= dv;
  int e1 = offs[v + 1];
  for (int e = offs[v]; e < e1; ++e) {
    int u = csrc[e];
    float du = dinv[u];
    loadv<VEC>(Z + (size_t)u * F + lane * VEC, tmp);
#pragma unroll
    for (int j = 0; j < VEC; ++j) acc[j] += tmp[j] * du;
  }
  ushort* o = Outb + (size_t)v * F + lane * VEC;
  if constexpr (VEC == 4) {
    uint2 w;
    w.x = (uint)f2bf(acc[0] * dv) | ((uint)f2bf(acc[1] * dv) << 16);
    w.y = (uint)f2bf(acc[2] * dv) | ((uint)f2bf(acc[3] * dv) << 16);
    *reinterpret_cast<uint2*>(o) = w;
  } else {
    uint w = (uint)f2bf(acc[0] * dv) | ((uint)f2bf(acc[1] * dv) << 16);
    *reinterpret_cast<uint*>(o) = w;
  }
}

// final aggregation on 20-wide z3, writes fp32 output + b3
__global__ __launch_bounds__(256) void k_aggfin(const ushort* __restrict__ Z,
                                                const int* __restrict__ offs, const int* __restrict__ csrc,
                                                const float* __restrict__ dinv, const float* __restrict__ b3,
                                                float* __restrict__ out) {
  int wave = threadIdx.x >> 6, lane = threadIdx.x & 63;
  int v = blockIdx.x * 4 + wave;
  if (v >= NN || lane >= 20) return;
  float dv = dinv[v];
  float acc = b2f(Z[(size_t)v * 32 + lane]) * dv;
  int e1 = offs[v + 1];
  for (int e = offs[v]; e < e1; ++e) {
    int u = csrc[e];
    acc += b2f(Z[(size_t)u * 32 + lane]) * dinv[u];
  }
  out[(size_t)v * 20 + lane] = acc * dv + b3[lane];
}

// ---------------- MFMA GEMM: [N,KTOT] x [KTOT,BNCOLS] with optional BN+ReLU epilogue ----------------
template<int KTOT, int BN, bool EPI>
__global__ __launch_bounds__(256) void k_gemm(const ushort* __restrict__ A,
                                              const ushort* __restrict__ Bt,   // [cols][KTOT]
                                              ushort* __restrict__ Out,
                                              const float* __restrict__ bnA,
                                              const float* __restrict__ bnB, int outW) {
  constexpr int BM = 128, BK = 64;
  constexpr int WN = (BN == 128) ? 64 : 16;
  constexpr int WM = 64;
  constexpr int FM = WM / 16, FN = WN / 16;
  __shared__ ushort Alds[BM * BK];
  __shared__ ushort Blds[BN * BK];
  int tid = threadIdx.x;
  int lane = tid & 63;
  int wave = tid >> 6;
  int wm = wave >> 1, wn = wave & 1;
  size_t row0 = (size_t)blockIdx.x * BM;
  int col0 = blockIdx.y * BN;

  f32x4 acc[FM][FN];
#pragma unroll
  for (int i = 0; i < FM; ++i)
#pragma unroll
    for (int j = 0; j < FN; ++j)
#pragma unroll
      for (int r = 0; r < 4; ++r) acc[i][j][r] = 0.0f;

  for (int k0 = 0; k0 < KTOT; k0 += BK) {
#pragma unroll
    for (int is = 0; is < 4; ++is) {
      int idx = is * 256 + tid;
      int r = idx >> 3, c = idx & 7;
      size_t gr = row0 + r; if (gr >= NN) gr = NN - 1;
      gload16(A + gr * KTOT + k0 + c * 8, &Alds[(size_t)(idx & ~63) * 8]);
    }
#pragma unroll
    for (int is = 0; is < BN / 32; ++is) {
      int idx = is * 256 + tid;
      int r = idx >> 3, c = idx & 7;
      gload16(Bt + (size_t)(col0 + r) * KTOT + k0 + c * 8, &Blds[(size_t)(idx & ~63) * 8]);
    }
    __syncthreads();
#pragma unroll
    for (int kk = 0; kk < BK; kk += 32) {
      short8 af[FM]; short8 bfr[FN];
#pragma unroll
      for (int fm = 0; fm < FM; ++fm)
        af[fm] = *reinterpret_cast<const short8*>(&Alds[(wm * WM + fm * 16 + (lane & 15)) * BK + kk + (lane >> 4) * 8]);
#pragma unroll
      for (int fn = 0; fn < FN; ++fn)
        bfr[fn] = *reinterpret_cast<const short8*>(&Blds[(wn * WN + fn * 16 + (lane & 15)) * BK + kk + (lane >> 4) * 8]);
#pragma unroll
      for (int fm = 0; fm < FM; ++fm)
#pragma unroll
        for (int fn = 0; fn < FN; ++fn)
          acc[fm][fn] = __builtin_amdgcn_mfma_f32_16x16x32_bf16(af[fm], bfr[fn], acc[fm][fn], 0, 0, 0);
    }
    __syncthreads();
  }

  int lr = (lane >> 4) * 4, lc = lane & 15;
#pragma unroll
  for (int fm = 0; fm < FM; ++fm) {
#pragma unroll
    for (int r = 0; r < 4; ++r) {
      size_t grow = row0 + wm * WM + fm * 16 + lr + r;
      if (grow >= NN) continue;
#pragma unroll
      for (int fn = 0; fn < FN; ++fn) {
        int gcol = col0 + wn * WN + fn * 16 + lc;
        float v = acc[fm][fn][r];
        if constexpr (EPI) v = fmaxf(v * bnA[gcol] + bnB[gcol], 0.0f);
        Out[grow * outW + gcol] = f2bf(v);
      }
    }
  }
}

extern "C" void kernel_launch(void* const* d_in, const int* in_sizes, int n_in,
                              void* d_out, int out_size, void* d_ws, size_t ws_size,
                              hipStream_t stream) {
  (void)in_sizes; (void)n_in; (void)out_size; (void)ws_size;
  const float* x     = (const float*)d_in[0];
  const int*   ei    = (const int*)d_in[1];
  const float* W0    = (const float*)d_in[2];
  const float* b0    = (const float*)d_in[3];
  const float* W1    = (const float*)d_in[4];
  const float* b1    = (const float*)d_in[5];
  const float* W2    = (const float*)d_in[6];
  const float* b2    = (const float*)d_in[7];
  const float* W3    = (const float*)d_in[8];
  const float* b3    = (const float*)d_in[9];
  const float* gamma = (const float*)d_in[10];
  const float* beta  = (const float*)d_in[11];
  const float* rm    = (const float*)d_in[12];
  const float* rv    = (const float*)d_in[13];
  const int* src = ei;
  const int* dst = ei + NE;
  float* out = (float*)d_out;

  char* ws = (char*)d_ws;
  size_t off = 0;
  auto alloc = [&](size_t bytes) -> void* {
    void* p = ws + off; off += (bytes + 255) & ~(size_t)255; return p;
  };
  int*    deg   = (int*)alloc(NN * 4);
  int*    cur   = (int*)alloc(NN * 4);
  int*    offs  = (int*)alloc((NN + 1) * (size_t)4);
  int*    bsums = (int*)alloc(512 * 4);
  int*    csrc  = (int*)alloc((size_t)NE * 4);
  float*  dinv  = (float*)alloc(NN * 4);
  ushort* W0t   = (ushort*)alloc(256 * 128 * 2);
  ushort* W1t   = (ushort*)alloc(256 * 256 * 2);
  ushort* W2t   = (ushort*)alloc(256 * 256 * 2);
  ushort* W3t   = (ushort*)alloc(32 * 256 * 2);
  float*  bnA   = (float*)alloc(3 * 256 * 4);
  float*  bnB   = (float*)alloc(3 * 256 * 4);
  ushort* bufS  = (ushort*)alloc((size_t)NN * 128 * 2);   // x_bf16 / z3
  ushort* bufA  = (ushort*)alloc((size_t)NN * 256 * 2);   // agg outputs
  ushort* bufB  = (ushort*)alloc((size_t)NN * 256 * 2);   // gemm outputs

  hipMemsetAsync(deg, 0, NN * 4, stream);
  hipMemsetAsync(cur, 0, NN * 4, stream);
  k_deg<<<2048, 256, 0, stream>>>(dst, deg);
  k_dinv<<<(NN + 255) / 256, 256, 0, stream>>>(deg, dinv);
  int nb = (NN + 255) / 256;   // 391
  k_scan1<<<nb, 256, 0, stream>>>(deg, offs, bsums);
  k_scan2<<<1, 512, 0, stream>>>(bsums, nb, offs);
  k_scan3<<<nb, 256, 0, stream>>>(offs, bsums);
  k_fill<<<2048, 256, 0, stream>>>(src, dst, offs, cur, csrc);
  k_prep<<<256, 256, 0, stream>>>(W0, W1, W2, W3, b0, b1, b2, gamma, beta, rm, rv,
                                  W0t, W1t, W2t, W3t, bnA, bnB);
  k_convx<<<2048, 256, 0, stream>>>((const float4*)x, (uint2*)bufS);

  const int aggBlocks = (NN + 3) / 4;   // 25000
  dim3 gMain((NN + 127) / 128, 2);
  dim3 gLast((NN + 127) / 128, 1);

  // L0: aggregate(x)[128] -> GEMM 128->256 (+bias+BN+ReLU)
  k_agg<128, 2><<<aggBlocks, 256, 0, stream>>>(bufS, offs, csrc, dinv, bufA);
  k_gemm<128, 128, true><<<gMain, 256, 0, stream>>>(bufA, W0t, bufB, bnA, bnB, 256);
  // L1
  k_agg<256, 4><<<aggBlocks, 256, 0, stream>>>(bufB, offs, csrc, dinv, bufA);
  k_gemm<256, 128, true><<<gMain, 256, 0, stream>>>(bufA, W1t, bufB, bnA + 256, bnB + 256, 256);
  // L2
  k_agg<256, 4><<<aggBlocks, 256, 0, stream>>>(bufB, offs, csrc, dinv, bufA);
  k_gemm<256, 128, true><<<gMain, 256, 0, stream>>>(bufA, W2t, bufB, bnA + 512, bnB + 512, 256);
  // L3: GEMM 256->20 (padded to 32, no epilogue), then aggregate + b3 -> fp32 out
  k_gemm<256, 32, false><<<gLast, 256, 0, stream>>>(bufB, W3t, bufS, nullptr, nullptr, 32);
  k_aggfin<<<aggBlocks, 256, 0, stream>>>(bufS, offs, csrc, dinv, b3, out);
}

// Round 3
// 673.888 us; speedup vs baseline: 1.4246x; 1.4246x over previous
//
#include <hip/hip_runtime.h>
#include <hip/hip_bf16.h>
#include <stdint.h>

#define NN 100000
#define NE 1600000
#define BNEPS 1e-5f

using short8 = __attribute__((ext_vector_type(8))) short;
using f32x4  = __attribute__((ext_vector_type(4))) float;

__device__ __forceinline__ float b2f(ushort u) {
  union { uint32_t u; float f; } c; c.u = ((uint32_t)u) << 16; return c.f;
}
__device__ __forceinline__ ushort f2bf(float f) {
  union { float f; uint32_t u; } c; c.f = f;
  uint32_t r = (c.u + 0x7FFFu + ((c.u >> 16) & 1u)) >> 16;
  return (ushort)r;
}
__device__ __forceinline__ void gload16(const void* g, void* lds) {
  __builtin_amdgcn_global_load_lds((const __attribute__((address_space(1))) void*)g,
                                   (__attribute__((address_space(3))) void*)lds,
                                   16, 0, 0);
}

// ---------------- CSR build ----------------
__global__ __launch_bounds__(256) void k_deg(const int* __restrict__ dst, int* __restrict__ deg) {
  int stride = gridDim.x * blockDim.x;
  for (int e = blockIdx.x * blockDim.x + threadIdx.x; e < NE; e += stride)
    atomicAdd(&deg[dst[e]], 1);
}

// scan1 also produces dinv
__global__ __launch_bounds__(256) void k_scan1(const int* __restrict__ deg, int* __restrict__ offs,
                                               int* __restrict__ bsums, float* __restrict__ dinv) {
  __shared__ int s[256];
  int t = threadIdx.x;
  int v = blockIdx.x * 256 + t;
  int d = (v < NN) ? deg[v] : 0;
  if (v < NN) dinv[v] = rsqrtf((float)d + 1.0f);
  s[t] = d; __syncthreads();
  int val = d;
  for (int sh = 1; sh < 256; sh <<= 1) {
    int tv = (t >= sh) ? s[t - sh] : 0;
    __syncthreads();
    val += tv; s[t] = val;
    __syncthreads();
  }
  if (v < NN) offs[v] = val - d;           // block-local exclusive
  if (t == 255) bsums[blockIdx.x] = val;   // block total
}

__global__ __launch_bounds__(512) void k_scan2(int* __restrict__ bsums, int nb, int* __restrict__ offs) {
  __shared__ int s[512];
  int t = threadIdx.x;
  int d = (t < nb) ? bsums[t] : 0;
  s[t] = d; __syncthreads();
  int val = d;
  for (int sh = 1; sh < 512; sh <<= 1) {
    int tv = (t >= sh) ? s[t - sh] : 0;
    __syncthreads();
    val += tv; s[t] = val;
    __syncthreads();
  }
  if (t < nb) bsums[t] = val;              // inclusive
  if (t == 0) offs[NN] = NE;
}

__global__ __launch_bounds__(256) void k_scan3(int* __restrict__ offs, const int* __restrict__ bsums) {
  int v = blockIdx.x * 256 + threadIdx.x;
  if (v < NN) { int b = v >> 8; if (b > 0) offs[v] += bsums[b - 1]; }
}

__global__ __launch_bounds__(256) void k_fill(const int* __restrict__ src, const int* __restrict__ dst,
                                              const int* __restrict__ offs, int* __restrict__ cur,
                                              int* __restrict__ csrc) {
  int stride = gridDim.x * blockDim.x;
  for (int e = blockIdx.x * blockDim.x + threadIdx.x; e < NE; e += stride) {
    int v = dst[e];
    int pos = offs[v] + atomicAdd(&cur[v], 1);
    csrc[pos] = src[e];
  }
}

// ---------------- weight prep ----------------
__global__ __launch_bounds__(256) void k_prep(
    const float* __restrict__ W0, const float* __restrict__ W1, const float* __restrict__ W2,
    const float* __restrict__ W3, const float* __restrict__ b0, const float* __restrict__ b1,
    const float* __restrict__ b2, const float* __restrict__ gamma, const float* __restrict__ beta,
    const float* __restrict__ rm, const float* __restrict__ rv,
    ushort* __restrict__ W0t, ushort* __restrict__ W1t, ushort* __restrict__ W2t,
    ushort* __restrict__ W3t, float* __restrict__ bnA, float* __restrict__ bnB) {
  int tid = blockIdx.x * blockDim.x + threadIdx.x;
  int nthr = gridDim.x * blockDim.x;
  for (int i = tid; i < 256 * 128; i += nthr) { int m = i >> 7, k = i & 127; W0t[i] = f2bf(W0[k * 256 + m]); }
  for (int i = tid; i < 256 * 256; i += nthr) {
    int m = i >> 8, k = i & 255;
    W1t[i] = f2bf(W1[k * 256 + m]);
    W2t[i] = f2bf(W2[k * 256 + m]);
  }
  for (int i = tid; i < 32 * 256; i += nthr) {
    int m = i >> 8, k = i & 255;
    W3t[i] = (m < 20) ? f2bf(W3[k * 20 + m]) : (ushort)0;
  }
  for (int i = tid; i < 3 * 256; i += nthr) {
    int l = i >> 8, c = i & 255;
    float A = gamma[i] * rsqrtf(rv[i] + BNEPS);
    float bb = (l == 0) ? b0[c] : (l == 1) ? b1[c] : b2[c];
    bnA[i] = A;
    bnB[i] = (bb - rm[i]) * A + beta[i];
  }
}

// ---------------- x -> bf16, pre-scaled by dinv[row] ----------------
__global__ __launch_bounds__(256) void k_convx(const float4* __restrict__ x, uint2* __restrict__ xb,
                                               const float* __restrict__ dinv) {
  int stride = gridDim.x * blockDim.x;
  const int n4 = NN * 128 / 4;
  for (int i = blockIdx.x * blockDim.x + threadIdx.x; i < n4; i += stride) {
    float4 f = x[i];
    float dv = dinv[i >> 5];   // 32 float4 per 128-wide row
    uint2 o;
    o.x = (uint)f2bf(f.x * dv) | ((uint)f2bf(f.y * dv) << 16);
    o.y = (uint)f2bf(f.z * dv) | ((uint)f2bf(f.w * dv) << 16);
    xb[i] = o;
  }
}

// ---------------- gather aggregation (one wave per node) ----------------
// Z rows are PRE-SCALED by dinv[u]:  out[v] = (zs[v] + sum_u zs[u]) * dinv[v]
//   (self term: zs[v]*dv = z[v]*dv^2  — correct)
template<int F, int VEC>
__global__ __launch_bounds__(256) void k_agg(const ushort* __restrict__ Z,
                                             const int* __restrict__ offs, const int* __restrict__ csrc,
                                             const float* __restrict__ dinv, ushort* __restrict__ Outb) {
  int wave = threadIdx.x >> 6, lane = threadIdx.x & 63;
  int v = blockIdx.x * 4 + wave;
  if (v >= NN) return;
  float dv = dinv[v];
  float acc[VEC];

  if constexpr (VEC == 4) {
    const uint2* Zq = reinterpret_cast<const uint2*>(Z);
    constexpr int RW = F / 4;           // uint2 per row
    uint2 qs = Zq[(size_t)v * RW + lane];
    acc[0] = b2f((ushort)(qs.x & 0xFFFF));
    acc[1] = b2f((ushort)(qs.x >> 16));
    acc[2] = b2f((ushort)(qs.y & 0xFFFF));
    acc[3] = b2f((ushort)(qs.y >> 16));
    int e = offs[v], e1 = offs[v + 1];
    for (; e + 4 <= e1; e += 4) {
      int u0 = csrc[e + 0], u1 = csrc[e + 1], u2 = csrc[e + 2], u3 = csrc[e + 3];
      uint2 q0 = Zq[(size_t)u0 * RW + lane];
      uint2 q1 = Zq[(size_t)u1 * RW + lane];
      uint2 q2 = Zq[(size_t)u2 * RW + lane];
      uint2 q3 = Zq[(size_t)u3 * RW + lane];
      acc[0] += (b2f((ushort)(q0.x & 0xFFFF)) + b2f((ushort)(q1.x & 0xFFFF)))
              + (b2f((ushort)(q2.x & 0xFFFF)) + b2f((ushort)(q3.x & 0xFFFF)));
      acc[1] += (b2f((ushort)(q0.x >> 16)) + b2f((ushort)(q1.x >> 16)))
              + (b2f((ushort)(q2.x >> 16)) + b2f((ushort)(q3.x >> 16)));
      acc[2] += (b2f((ushort)(q0.y & 0xFFFF)) + b2f((ushort)(q1.y & 0xFFFF)))
              + (b2f((ushort)(q2.y & 0xFFFF)) + b2f((ushort)(q3.y & 0xFFFF)));
      acc[3] += (b2f((ushort)(q0.y >> 16)) + b2f((ushort)(q1.y >> 16)))
              + (b2f((ushort)(q2.y >> 16)) + b2f((ushort)(q3.y >> 16)));
    }
    for (; e < e1; ++e) {
      uint2 q = Zq[(size_t)csrc[e] * RW + lane];
      acc[0] += b2f((ushort)(q.x & 0xFFFF));
      acc[1] += b2f((ushort)(q.x >> 16));
      acc[2] += b2f((ushort)(q.y & 0xFFFF));
      acc[3] += b2f((ushort)(q.y >> 16));
    }
    uint2 w;
    w.x = (uint)f2bf(acc[0] * dv) | ((uint)f2bf(acc[1] * dv) << 16);
    w.y = (uint)f2bf(acc[2] * dv) | ((uint)f2bf(acc[3] * dv) << 16);
    reinterpret_cast<uint2*>(Outb)[(size_t)v * RW + lane] = w;
  } else {
    const uint* Zq = reinterpret_cast<const uint*>(Z);
    constexpr int RW = F / 2;           // uint per row
    uint qs = Zq[(size_t)v * RW + lane];
    acc[0] = b2f((ushort)(qs & 0xFFFF));
    acc[1] = b2f((ushort)(qs >> 16));
    int e = offs[v], e1 = offs[v + 1];
    for (; e + 4 <= e1; e += 4) {
      int u0 = csrc[e + 0], u1 = csrc[e + 1], u2 = csrc[e + 2], u3 = csrc[e + 3];
      uint q0 = Zq[(size_t)u0 * RW + lane];
      uint q1 = Zq[(size_t)u1 * RW + lane];
      uint q2 = Zq[(size_t)u2 * RW + lane];
      uint q3 = Zq[(size_t)u3 * RW + lane];
      acc[0] += (b2f((ushort)(q0 & 0xFFFF)) + b2f((ushort)(q1 & 0xFFFF)))
              + (b2f((ushort)(q2 & 0xFFFF)) + b2f((ushort)(q3 & 0xFFFF)));
      acc[1] += (b2f((ushort)(q0 >> 16)) + b2f((ushort)(q1 >> 16)))
              + (b2f((ushort)(q2 >> 16)) + b2f((ushort)(q3 >> 16)));
    }
    for (; e < e1; ++e) {
      uint q = Zq[(size_t)csrc[e] * RW + lane];
      acc[0] += b2f((ushort)(q & 0xFFFF));
      acc[1] += b2f((ushort)(q >> 16));
    }
    uint w = (uint)f2bf(acc[0] * dv) | ((uint)f2bf(acc[1] * dv) << 16);
    reinterpret_cast<uint*>(Outb)[(size_t)v * RW + lane] = w;
  }
}

// final aggregation on 32-padded z3 (pre-scaled), 2 nodes per wave, fp32 out + b3
__global__ __launch_bounds__(256) void k_aggfin(const ushort* __restrict__ Z,
                                                const int* __restrict__ offs, const int* __restrict__ csrc,
                                                const float* __restrict__ dinv, const float* __restrict__ b3,
                                                float* __restrict__ out) {
  int wave = threadIdx.x >> 6, lane = threadIdx.x & 63;
  int half = lane >> 5, fl = lane & 31;
  int v = blockIdx.x * 8 + wave * 2 + half;
  if (v >= NN) return;
  float dv = dinv[v];
  float acc = b2f(Z[(size_t)v * 32 + fl]);
  int e = offs[v], e1 = offs[v + 1];
  for (; e + 4 <= e1; e += 4) {
    int u0 = csrc[e + 0], u1 = csrc[e + 1], u2 = csrc[e + 2], u3 = csrc[e + 3];
    float t0 = b2f(Z[(size_t)u0 * 32 + fl]);
    float t1 = b2f(Z[(size_t)u1 * 32 + fl]);
    float t2 = b2f(Z[(size_t)u2 * 32 + fl]);
    float t3 = b2f(Z[(size_t)u3 * 32 + fl]);
    acc += (t0 + t1) + (t2 + t3);
  }
  for (; e < e1; ++e) acc += b2f(Z[(size_t)csrc[e] * 32 + fl]);
  if (fl < 20) out[(size_t)v * 20 + fl] = acc * dv + b3[fl];
}

// ---------------- MFMA GEMM with optional BN+ReLU epilogue and optional dinv pre-scale ----------------
template<int KTOT, int BN, bool EPI, bool SCALE>
__global__ __launch_bounds__(256) void k_gemm(const ushort* __restrict__ A,
                                              const ushort* __restrict__ Bt,   // [cols][KTOT]
                                              ushort* __restrict__ Out,
                                              const float* __restrict__ bnA,
                                              const float* __restrict__ bnB,
                                              const float* __restrict__ dinv, int outW) {
  constexpr int BM = 128, BK = 64;
  constexpr int WN = (BN == 128) ? 64 : 16;
  constexpr int WM = 64;
  constexpr int FM = WM / 16, FN = WN / 16;
  __shared__ ushort Alds[BM * BK];
  __shared__ ushort Blds[BN * BK];
  int tid = threadIdx.x;
  int lane = tid & 63;
  int wave = tid >> 6;
  int wm = wave >> 1, wn = wave & 1;
  size_t row0 = (size_t)blockIdx.x * BM;
  int col0 = blockIdx.y * BN;

  f32x4 acc[FM][FN];
#pragma unroll
  for (int i = 0; i < FM; ++i)
#pragma unroll
    for (int j = 0; j < FN; ++j)
#pragma unroll
      for (int r = 0; r < 4; ++r) acc[i][j][r] = 0.0f;

  for (int k0 = 0; k0 < KTOT; k0 += BK) {
#pragma unroll
    for (int is = 0; is < 4; ++is) {
      int idx = is * 256 + tid;
      int r = idx >> 3, c = idx & 7;
      size_t gr = row0 + r; if (gr >= NN) gr = NN - 1;
      gload16(A + gr * KTOT + k0 + c * 8, &Alds[(size_t)(idx & ~63) * 8]);
    }
#pragma unroll
    for (int is = 0; is < BN / 32; ++is) {
      int idx = is * 256 + tid;
      int r = idx >> 3, c = idx & 7;
      gload16(Bt + (size_t)(col0 + r) * KTOT + k0 + c * 8, &Blds[(size_t)(idx & ~63) * 8]);
    }
    __syncthreads();
#pragma unroll
    for (int kk = 0; kk < BK; kk += 32) {
      short8 af[FM]; short8 bfr[FN];
#pragma unroll
      for (int fm = 0; fm < FM; ++fm)
        af[fm] = *reinterpret_cast<const short8*>(&Alds[(wm * WM + fm * 16 + (lane & 15)) * BK + kk + (lane >> 4) * 8]);
#pragma unroll
      for (int fn = 0; fn < FN; ++fn)
        bfr[fn] = *reinterpret_cast<const short8*>(&Blds[(wn * WN + fn * 16 + (lane & 15)) * BK + kk + (lane >> 4) * 8]);
#pragma unroll
      for (int fm = 0; fm < FM; ++fm)
#pragma unroll
        for (int fn = 0; fn < FN; ++fn)
          acc[fm][fn] = __builtin_amdgcn_mfma_f32_16x16x32_bf16(af[fm], bfr[fn], acc[fm][fn], 0, 0, 0);
    }
    __syncthreads();
  }

  int lr = (lane >> 4) * 4, lc = lane & 15;
#pragma unroll
  for (int fm = 0; fm < FM; ++fm) {
#pragma unroll
    for (int r = 0; r < 4; ++r) {
      size_t grow = row0 + wm * WM + fm * 16 + lr + r;
      if (grow >= NN) continue;
      float ds = 1.0f;
      if constexpr (SCALE) ds = dinv[grow];
#pragma unroll
      for (int fn = 0; fn < FN; ++fn) {
        int gcol = col0 + wn * WN + fn * 16 + lc;
        float v = acc[fm][fn][r];
        if constexpr (EPI) v = fmaxf(v * bnA[gcol] + bnB[gcol], 0.0f);
        if constexpr (SCALE) v *= ds;
        Out[grow * outW + gcol] = f2bf(v);
      }
    }
  }
}

extern "C" void kernel_launch(void* const* d_in, const int* in_sizes, int n_in,
                              void* d_out, int out_size, void* d_ws, size_t ws_size,
                              hipStream_t stream) {
  (void)in_sizes; (void)n_in; (void)out_size; (void)ws_size;
  const float* x     = (const float*)d_in[0];
  const int*   ei    = (const int*)d_in[1];
  const float* W0    = (const float*)d_in[2];
  const float* b0    = (const float*)d_in[3];
  const float* W1    = (const float*)d_in[4];
  const float* b1    = (const float*)d_in[5];
  const float* W2    = (const float*)d_in[6];
  const float* b2    = (const float*)d_in[7];
  const float* W3    = (const float*)d_in[8];
  const float* b3    = (const float*)d_in[9];
  const float* gamma = (const float*)d_in[10];
  const float* beta  = (const float*)d_in[11];
  const float* rm    = (const float*)d_in[12];
  const float* rv    = (const float*)d_in[13];
  const int* src = ei;
  const int* dst = ei + NE;
  float* out = (float*)d_out;

  char* ws = (char*)d_ws;
  size_t off = 0;
  auto alloc = [&](size_t bytes) -> void* {
    void* p = ws + off; off += (bytes + 255) & ~(size_t)255; return p;
  };
  int*    deg   = (int*)alloc(NN * 4);
  int*    cur   = (int*)alloc(NN * 4);
  int*    offs  = (int*)alloc((NN + 1) * (size_t)4);
  int*    bsums = (int*)alloc(512 * 4);
  int*    csrc  = (int*)alloc((size_t)NE * 4);
  float*  dinv  = (float*)alloc(NN * 4);
  ushort* W0t   = (ushort*)alloc(256 * 128 * 2);
  ushort* W1t   = (ushort*)alloc(256 * 256 * 2);
  ushort* W2t   = (ushort*)alloc(256 * 256 * 2);
  ushort* W3t   = (ushort*)alloc(32 * 256 * 2);
  float*  bnA   = (float*)alloc(3 * 256 * 4);
  float*  bnB   = (float*)alloc(3 * 256 * 4);
  ushort* bufS  = (ushort*)alloc((size_t)NN * 128 * 2);   // x_bf16*dinv / z3*dinv
  ushort* bufA  = (ushort*)alloc((size_t)NN * 256 * 2);   // agg outputs
  ushort* bufB  = (ushort*)alloc((size_t)NN * 256 * 2);   // gemm outputs

  hipMemsetAsync(deg, 0, NN * 4, stream);
  hipMemsetAsync(cur, 0, NN * 4, stream);
  k_deg<<<2048, 256, 0, stream>>>(dst, deg);
  int nb = (NN + 255) / 256;   // 391
  k_scan1<<<nb, 256, 0, stream>>>(deg, offs, bsums, dinv);
  k_scan2<<<1, 512, 0, stream>>>(bsums, nb, offs);
  k_scan3<<<nb, 256, 0, stream>>>(offs, bsums);
  k_fill<<<2048, 256, 0, stream>>>(src, dst, offs, cur, csrc);
  k_prep<<<256, 256, 0, stream>>>(W0, W1, W2, W3, b0, b1, b2, gamma, beta, rm, rv,
                                  W0t, W1t, W2t, W3t, bnA, bnB);
  k_convx<<<2048, 256, 0, stream>>>((const float4*)x, (uint2*)bufS, dinv);

  const int aggBlocks = (NN + 3) / 4;   // 25000
  dim3 gMain((NN + 127) / 128, 2);
  dim3 gLast((NN + 127) / 128, 1);

  // L0: aggregate(x*dinv)[128] -> GEMM 128->256 (+BN+ReLU, out *= dinv)
  k_agg<128, 2><<<aggBlocks, 256, 0, stream>>>(bufS, offs, csrc, dinv, bufA);
  k_gemm<128, 128, true, true><<<gMain, 256, 0, stream>>>(bufA, W0t, bufB, bnA, bnB, dinv, 256);
  // L1 (out *= dinv, feeds agg2)
  k_agg<256, 4><<<aggBlocks, 256, 0, stream>>>(bufB, offs, csrc, dinv, bufA);
  k_gemm<256, 128, true, true><<<gMain, 256, 0, stream>>>(bufA, W1t, bufB, bnA + 256, bnB + 256, dinv, 256);
  // L2 (NO dinv scale — output feeds GEMM3 directly)
  k_agg<256, 4><<<aggBlocks, 256, 0, stream>>>(bufB, offs, csrc, dinv, bufA);
  k_gemm<256, 128, true, false><<<gMain, 256, 0, stream>>>(bufA, W2t, bufB, bnA + 512, bnB + 512, nullptr, 256);
  // L3: GEMM 256->20 (padded 32, out *= dinv), then aggregate + b3 -> fp32 out
  k_gemm<256, 32, false, true><<<gLast, 256, 0, stream>>>(bufB, W3t, bufS, nullptr, nullptr, dinv, 32);
  k_aggfin<<<(NN + 7) / 8, 256, 0, stream>>>(bufS, offs, csrc, dinv, b3, out);
}